// Round 4
// baseline (1240.113 us; speedup 1.0000x reference)
//
#include <hip/hip_runtime.h>
#include <cmath>

static constexpr int kHid = 1152;
static constexpr int kM   = 4096;   // B * N tokens

typedef __bf16 bf16x8 __attribute__((ext_vector_type(8)));
typedef float  f32x4  __attribute__((ext_vector_type(4)));

struct BicW { float w[16][4]; };

__device__ __forceinline__ float dev_silu(float x) { return x / (1.0f + expf(-x)); }
__device__ __forceinline__ float dev_gelu(float x) {
  float u = 0.7978845608028654f * (x + 0.044715f * x * x * x);
  return 0.5f * x * (1.0f + tanhf(u));
}

__device__ __forceinline__ void glds16(const void* g, void* l) {
  __builtin_amdgcn_global_load_lds(
      (const __attribute__((address_space(1))) unsigned int*)g,
      (__attribute__((address_space(3))) unsigned int*)l, 16, 0, 0);
}

// ---------------- patch embed + bicubic pos embed (fp32 h) ----------------
__global__ __launch_bounds__(256) void k_patch_pos(
    const float* __restrict__ x, const float* __restrict__ pw,
    const float* __restrict__ pb, const float* __restrict__ pos,
    float* __restrict__ h, BicW W)
{
  const int total = kM * kHid;
  for (int idx = blockIdx.x * blockDim.x + threadIdx.x; idx < total;
       idx += gridDim.x * blockDim.x) {
    int c  = idx % kHid;
    int t  = idx / kHid;
    int b  = t >> 8;
    int gy = (t >> 4) & 15;
    int gx = t & 15;
    float acc = pb[c];
    const float* xb  = x + (size_t)b * 4 * 1024;
    const float* pwc = pw + (size_t)c * 16;
#pragma unroll
    for (int ic = 0; ic < 4; ic++)
#pragma unroll
      for (int p = 0; p < 2; p++)
#pragma unroll
        for (int q = 0; q < 2; q++)
          acc += xb[ic * 1024 + (gy * 2 + p) * 32 + gx * 2 + q] *
                 pwc[(ic * 2 + p) * 2 + q];
    float pe = 0.f;
#pragma unroll
    for (int iy = 0; iy < 4; iy++) {
      float ra = 0.f;
#pragma unroll
      for (int ix = 0; ix < 4; ix++)
        ra += W.w[gx][ix] * pos[(iy * 4 + ix) * kHid + c];
      pe += W.w[gy][iy] * ra;
    }
    h[idx] = acc + pe;
  }
}

// ---------------- timestep embedding, K-split: grid (18, B) ----------------
__global__ __launch_bounds__(256) void k_temb1(
    const float* __restrict__ t, const float* __restrict__ w1,
    const float* __restrict__ b1, float* __restrict__ hid1)
{
  int b  = blockIdx.y;
  int j0 = blockIdx.x * 64;
  int tid = threadIdx.x;
  __shared__ float e[256];
  if (tid < 128) {
    float fr  = expf(-9.210340371976184f * (float)tid / 128.0f);
    float arg = t[b] * fr;
    e[tid]       = cosf(arg);
    e[tid + 128] = sinf(arg);
  }
  __syncthreads();
  int j = tid & 63, ks = tid >> 6;
  float acc = 0.f;
#pragma unroll 4
  for (int k = ks * 64; k < ks * 64 + 64; k++)
    acc += e[k] * w1[k * kHid + j0 + j];
  __shared__ float part[4][64];
  part[ks][j] = acc;
  __syncthreads();
  if (ks == 0) {
    float v = part[0][j] + part[1][j] + part[2][j] + part[3][j] + b1[j0 + j];
    hid1[b * kHid + j0 + j] = dev_silu(v);
  }
}

__global__ __launch_bounds__(256) void k_temb2(
    const float* __restrict__ hid1, const float* __restrict__ w2,
    const float* __restrict__ b2, const float* __restrict__ ytab,
    const int* __restrict__ y, float* __restrict__ c, float* __restrict__ sc)
{
  int b  = blockIdx.y;
  int j0 = blockIdx.x * 64;
  __shared__ float hs[kHid];
  for (int k = threadIdx.x; k < kHid; k += 256) hs[k] = hid1[b * kHid + k];
  __syncthreads();
  int j = threadIdx.x & 63, ks = threadIdx.x >> 6;
  float acc = 0.f;
#pragma unroll 4
  for (int k = ks * 288; k < ks * 288 + 288; k++)
    acc += hs[k] * w2[(size_t)k * kHid + j0 + j];
  __shared__ float part[4][64];
  part[ks][j] = acc;
  __syncthreads();
  if (ks == 0) {
    int jj = j0 + j;
    float v = part[0][j] + part[1][j] + part[2][j] + part[3][j] + b2[jj] +
              ytab[(size_t)y[b] * kHid + jj];
    c[b * kHid + jj]  = v;
    sc[b * kHid + jj] = dev_silu(v);
  }
}

// ------- small matmul (16 x 1152) @ (1152 x Nout) + bias, K-split: grid (Nout/64, B)
__global__ __launch_bounds__(256) void k_ada(
    const float* __restrict__ scb, const float* __restrict__ w,
    const float* __restrict__ bias, float* __restrict__ out, int Nout)
{
  int b  = blockIdx.y;
  int j0 = blockIdx.x * 64;
  __shared__ float cs[kHid];
  for (int k = threadIdx.x; k < kHid; k += 256) cs[k] = scb[b * kHid + k];
  __syncthreads();
  int j = threadIdx.x & 63, ks = threadIdx.x >> 6;
  float acc = 0.f;
#pragma unroll 4
  for (int k = ks * 288; k < ks * 288 + 288; k++)
    acc += cs[k] * w[(size_t)k * Nout + j0 + j];
  __shared__ float part[4][64];
  part[ks][j] = acc;
  __syncthreads();
  if (ks == 0)
    out[(size_t)b * Nout + j0 + j] =
        part[0][j] + part[1][j] + part[2][j] + part[3][j] + bias[j0 + j];
}

// ------- fused weight convert+transpose for 4 matrices: W[K,N] f32 -> Wt[N,K] bf16
struct ConvDesc { const float* src; __bf16* dst; int K, N, tilesX; int start; };
struct ConvDescs { ConvDesc d[4]; };

__global__ __launch_bounds__(256) void k_convw4(ConvDescs cd)
{
  int bid = blockIdx.x;
  int e = 0;
#pragma unroll
  for (int i = 1; i < 4; i++) if (bid >= cd.d[i].start) e = i;
  const ConvDesc& D = cd.d[e];
  int lid = bid - D.start;
  int tx = lid % D.tilesX, ty = lid / D.tilesX;
  int n0 = tx * 32, k0 = ty * 32;
  __shared__ float tile[32][33];
  int c = threadIdx.x & 31, r = threadIdx.x >> 5;   // 8 rows per pass
#pragma unroll
  for (int i = 0; i < 32; i += 8)
    tile[r + i][c] = D.src[(size_t)(k0 + r + i) * D.N + n0 + c];
  __syncthreads();
#pragma unroll
  for (int i = 0; i < 32; i += 8) {
    int nn = r + i;
    D.dst[(size_t)(n0 + nn) * D.K + k0 + c] = (__bf16)tile[c][nn];
  }
}

// ---------------- LN + modulate -> bf16 ----------------
__global__ __launch_bounds__(256) void k_ln_mod(
    const float* __restrict__ h, const float* __restrict__ mod, int mstride,
    int sh_off, int sc_off, __bf16* __restrict__ out)
{
  int token = blockIdx.x;
  int b = token >> 8;
  const float* x = h + (size_t)token * kHid;
  float s = 0.f, ss = 0.f;
  for (int c = threadIdx.x; c < kHid; c += 256) {
    float v = x[c]; s += v; ss += v * v;
  }
#pragma unroll
  for (int o = 32; o > 0; o >>= 1) {
    s += __shfl_down(s, o, 64); ss += __shfl_down(ss, o, 64);
  }
  __shared__ float red[2][4];
  __shared__ float stats[2];
  int wave = threadIdx.x >> 6, lane = threadIdx.x & 63;
  if (lane == 0) { red[0][wave] = s; red[1][wave] = ss; }
  __syncthreads();
  if (threadIdx.x == 0) {
    float S  = red[0][0] + red[0][1] + red[0][2] + red[0][3];
    float SS = red[1][0] + red[1][1] + red[1][2] + red[1][3];
    float mean = S * (1.0f / kHid);
    float var  = SS * (1.0f / kHid) - mean * mean;
    stats[0] = mean;
    stats[1] = rsqrtf(var + 1e-6f);
  }
  __syncthreads();
  float mean = stats[0], rstd = stats[1];
  const float* shv = mod + (size_t)b * mstride + sh_off;
  const float* scv = mod + (size_t)b * mstride + sc_off;
  __bf16* o = out + (size_t)token * kHid;
  for (int c = threadIdx.x; c < kHid; c += 256) {
    float v = (x[c] - mean) * rstd;
    o[c] = (__bf16)(v * (1.f + scv[c]) + shv[c]);
  }
}

// ---------------- bf16 MFMA GEMM: C[M,N] = A[M,K](bf16) @ Wt[N,K]^T(bf16) + bias ----
// MODE 0: C=bf16 plain   MODE 1: C=bf16 gelu
// MODE 2: split-K atomic: C(f32) += gate[b]*(acc + bias(z==0 only))  [unsafeAtomicAdd]
template<int RB, int CB, int MODE, typename OutT>
__global__ __launch_bounds__(256) void mfma_gemm(
    const __bf16* __restrict__ A, const __bf16* __restrict__ Wt,
    const float* __restrict__ bias, OutT* C,
    const float* __restrict__ gate, int gstride,
    int Kslice, int Ktot, int Nout)
{
  constexpr int BM = RB * 32;
  constexpr int BN = CB * 32;
  __shared__ __attribute__((aligned(16))) __bf16 As[BM * 32];
  __shared__ __attribute__((aligned(16))) __bf16 Bs[BN * 32];

  const int tid  = threadIdx.x;
  const int lane = tid & 63;
  const int wv   = tid >> 6;
  const int wy   = wv >> 1, wx = wv & 1;
  const int l15  = lane & 15;
  const int quad = lane >> 4;
  const int m0   = blockIdx.y * BM;
  const int n0   = blockIdx.x * BN;
  const int kbase = blockIdx.z * Kslice;

  f32x4 acc[RB][CB] = {};

  const int arow0 = tid >> 2;          // chunk row
  const int akc   = (tid & 3) * 8;     // bf16 elems within row

  for (int k0 = kbase; k0 < kbase + Kslice; k0 += 32) {
#pragma unroll
    for (int p = 0; p < BM / 64; p++) {
      int row = arow0 + p * 64;
      glds16(A + (size_t)(m0 + row) * Ktot + k0 + akc, &As[(row * 32) + akc]);
    }
#pragma unroll
    for (int p = 0; p < BN / 64; p++) {
      int row = arow0 + p * 64;
      glds16(Wt + (size_t)(n0 + row) * Ktot + k0 + akc, &Bs[(row * 32) + akc]);
    }
    __syncthreads();

    bf16x8 af[RB], bf[CB];
#pragma unroll
    for (int r = 0; r < RB; r++)
      af[r] = *(const bf16x8*)&As[(wy * RB * 16 + r * 16 + l15) * 32 + quad * 8];
#pragma unroll
    for (int c2 = 0; c2 < CB; c2++)
      bf[c2] = *(const bf16x8*)&Bs[(wx * CB * 16 + c2 * 16 + l15) * 32 + quad * 8];
#pragma unroll
    for (int r = 0; r < RB; r++)
#pragma unroll
      for (int c2 = 0; c2 < CB; c2++)
        acc[r][c2] = __builtin_amdgcn_mfma_f32_16x16x32_bf16(af[r], bf[c2], acc[r][c2], 0, 0, 0);
    __syncthreads();
  }

  const int bidx = m0 >> 8;
  const bool addb = (blockIdx.z == 0);
#pragma unroll
  for (int c2 = 0; c2 < CB; c2++) {
    int col = n0 + wx * CB * 16 + c2 * 16 + l15;
    float bcol = addb ? bias[col] : 0.f;
    float gv = (MODE == 2) ? gate[(size_t)bidx * gstride + col] : 0.f;
#pragma unroll
    for (int r = 0; r < RB; r++) {
      int mbase = m0 + wy * RB * 16 + r * 16 + quad * 4;
#pragma unroll
      for (int reg = 0; reg < 4; reg++) {
        float v = acc[r][c2][reg] + bcol;
        size_t off = (size_t)(mbase + reg) * Nout + col;
        if (MODE == 0) C[off] = (OutT)v;
        if (MODE == 1) C[off] = (OutT)dev_gelu(v);
        if (MODE == 2) unsafeAtomicAdd((float*)&C[off], gv * v);
      }
    }
  }
}

// ---------------- neighborhood attention (WIN=4, 16 heads, dh=72), bf16 io ------
__global__ __launch_bounds__(256) void k_attn(const __bf16* __restrict__ qkv,
                                              __bf16* __restrict__ out)
{
  int token = blockIdx.x;
  int b = token >> 8;
  int i = (token >> 4) & 15;
  int j = token & 15;
  int si = min(max(i - 2, 0), 12);
  int sj = min(max(j - 2, 0), 12);
  __shared__ float att[16][17];
  __shared__ float prob[16][17];

  int hh = threadIdx.x >> 4;
  int pq = threadIdx.x & 15;
  int ni = si + (pq >> 2);
  int nj = sj + (pq & 3);
  int ntok = (b << 8) | (ni << 4) | nj;
  const __bf16* qp = qkv + (size_t)token * 3456 + hh * 72;
  const __bf16* kp = qkv + (size_t)ntok  * 3456 + kHid + hh * 72;
  float s = 0.f;
#pragma unroll
  for (int dc = 0; dc < 9; dc++) {
    bf16x8 qv = *(const bf16x8*)(qp + dc * 8);
    bf16x8 kv = *(const bf16x8*)(kp + dc * 8);
#pragma unroll
    for (int d = 0; d < 8; d++) s += (float)qv[d] * (float)kv[d];
  }
  att[hh][pq] = s * 0.11785113019775793f;  // 72^-0.5
  __syncthreads();
  if (threadIdx.x < 16) {
    int hd = threadIdx.x;
    float m = att[hd][0];
    for (int e2 = 1; e2 < 16; e2++) m = fmaxf(m, att[hd][e2]);
    float sum = 0.f;
    for (int e2 = 0; e2 < 16; e2++) {
      float ex = expf(att[hd][e2] - m);
      prob[hd][e2] = ex;
      sum += ex;
    }
    float inv = 1.f / sum;
    for (int e2 = 0; e2 < 16; e2++) prob[hd][e2] *= inv;
  }
  __syncthreads();
  // PV: 144 active threads, (head, d-chunk of 8)
  if (threadIdx.x < 144) {
    int hd = threadIdx.x / 9;
    int dc = threadIdx.x - hd * 9;
    float a8[8] = {};
#pragma unroll
    for (int e2 = 0; e2 < 16; e2++) {
      int nt = (b << 8) | ((si + (e2 >> 2)) << 4) | (sj + (e2 & 3));
      bf16x8 vv = *(const bf16x8*)(qkv + (size_t)nt * 3456 + 2304 + hd * 72 + dc * 8);
      float p = prob[hd][e2];
#pragma unroll
      for (int d = 0; d < 8; d++) a8[d] += p * (float)vv[d];
    }
    bf16x8 ov;
#pragma unroll
    for (int d = 0; d < 8; d++) ov[d] = (__bf16)a8[d];
    *(bf16x8*)(out + (size_t)token * kHid + hd * 72 + dc * 8) = ov;
  }
}

// ---------------- final: LN + modulate + (1152->32) + unpatchify ----------------
__global__ __launch_bounds__(256) void k_final(
    const float* __restrict__ h, const float* __restrict__ flm,
    const float* __restrict__ fw, const float* __restrict__ fb,
    float* __restrict__ out)
{
  int token = blockIdx.x;
  int b = token >> 8;
  const float* x = h + (size_t)token * kHid;
  float s = 0.f, ss = 0.f;
  for (int c = threadIdx.x; c < kHid; c += 256) { float v = x[c]; s += v; ss += v * v; }
#pragma unroll
  for (int o = 32; o > 0; o >>= 1) {
    s += __shfl_down(s, o, 64); ss += __shfl_down(ss, o, 64);
  }
  __shared__ float red[2][4];
  __shared__ float stats[2];
  __shared__ float xs[kHid];
  int wave = threadIdx.x >> 6, lane = threadIdx.x & 63;
  if (lane == 0) { red[0][wave] = s; red[1][wave] = ss; }
  __syncthreads();
  if (threadIdx.x == 0) {
    float S  = red[0][0] + red[0][1] + red[0][2] + red[0][3];
    float SS = red[1][0] + red[1][1] + red[1][2] + red[1][3];
    float mean = S * (1.0f / kHid);
    float var  = SS * (1.0f / kHid) - mean * mean;
    stats[0] = mean; stats[1] = rsqrtf(var + 1e-6f);
  }
  __syncthreads();
  float mean = stats[0], rstd = stats[1];
  const float* shv = flm + (size_t)b * 2304;
  const float* scv = shv + kHid;
  for (int c = threadIdx.x; c < kHid; c += 256)
    xs[c] = ((x[c] - mean) * rstd) * (1.f + scv[c]) + shv[c];
  __syncthreads();
  if (threadIdx.x < 32) {
    int jj = threadIdx.x;
    float acc = fb[jj];
    for (int k = 0; k < kHid; k++) acc += xs[k] * fw[k * 32 + jj];
    int p = jj >> 4, q = (jj >> 3) & 1, cc = jj & 7;
    int gy = (token >> 4) & 15, gx = token & 15;
    out[(((size_t)b * 8 + cc) * 32 + (gy * 2 + p)) * 32 + (gx * 2 + q)] = acc;
  }
}

extern "C" void kernel_launch(void* const* d_in, const int* in_sizes, int n_in,
                              void* d_out, int out_size, void* d_ws, size_t ws_size,
                              hipStream_t stream)
{
  const float* x        = (const float*)d_in[0];
  const float* t        = (const float*)d_in[1];
  const int*   y        = (const int*)  d_in[2];
  const float* pos      = (const float*)d_in[3];
  const float* patch_w  = (const float*)d_in[4];
  const float* patch_b  = (const float*)d_in[5];
  const float* t_w1     = (const float*)d_in[6];
  const float* t_b1     = (const float*)d_in[7];
  const float* t_w2     = (const float*)d_in[8];
  const float* t_b2     = (const float*)d_in[9];
  const float* y_table  = (const float*)d_in[10];
  const float* ada_w    = (const float*)d_in[11];
  const float* ada_b    = (const float*)d_in[12];
  const float* qkv_w    = (const float*)d_in[13];
  const float* qkv_b    = (const float*)d_in[14];
  const float* proj_w   = (const float*)d_in[15];
  const float* proj_b   = (const float*)d_in[16];
  const float* mlp_w1   = (const float*)d_in[17];
  const float* mlp_b1   = (const float*)d_in[18];
  const float* mlp_w2   = (const float*)d_in[19];
  const float* mlp_b2   = (const float*)d_in[20];
  const float* fl_ada_w = (const float*)d_in[21];
  const float* fl_ada_b = (const float*)d_in[22];
  const float* fl_w     = (const float*)d_in[23];
  const float* fl_b     = (const float*)d_in[24];
  float* out = (float*)d_out;

  // workspace carve-up
  float* ws   = (float*)d_ws;
  float*  h    = ws;                                   // 4096*1152 f32
  __bf16* xmod = (__bf16*)(h + (size_t)4096 * 1152);   // 4096*1152 bf16
  __bf16* big  = xmod + (size_t)4096 * 1152;           // 4096*4608 bf16
  __bf16* wq   = big  + (size_t)4096 * 4608;           // 3456*1152 bf16
  __bf16* wp   = wq   + (size_t)3456 * 1152;           // 1152*1152 bf16
  __bf16* wm1  = wp   + (size_t)1152 * 1152;           // 4608*1152 bf16
  __bf16* wm2  = wm1  + (size_t)4608 * 1152;           // 1152*4608 bf16
  float*  cbuf = (float*)(wm2 + (size_t)1152 * 4608);  // 16*1152
  float*  scb  = cbuf + 16 * 1152;
  float*  hid1 = scb  + 16 * 1152;
  float*  mod  = hid1 + 16 * 1152;                     // 16*6912
  float*  flm  = mod  + 16 * 6912;                     // 16*2304

  // bicubic (Keys a=-0.5) 4->16 resize weights, jax semantics, row-normalized
  BicW W;
  for (int o = 0; o < 16; o++) {
    double sf = (o + 0.5) * 0.25 - 0.5;
    double wd[4]; double tot = 0.0;
    const double a = -0.5;
    for (int i = 0; i < 4; i++) {
      double d = fabs(sf - (double)i);
      double v;
      if (d <= 1.0)      v = ((a + 2.0) * d - (a + 3.0)) * d * d + 1.0;
      else if (d < 2.0)  v = a * (((d - 5.0) * d + 8.0) * d - 4.0);
      else               v = 0.0;
      wd[i] = v; tot += v;
    }
    for (int i = 0; i < 4; i++) W.w[o][i] = (float)(wd[i] / tot);
  }

  k_patch_pos<<<4608, 256, 0, stream>>>(x, patch_w, patch_b, pos, h, W);
  k_temb1<<<dim3(18, 16), 256, 0, stream>>>(t, t_w1, t_b1, hid1);
  k_temb2<<<dim3(18, 16), 256, 0, stream>>>(hid1, t_w2, t_b2, y_table, y, cbuf, scb);

  for (int l = 0; l < 2; l++) {
    // fused weight convert: qkv(108x36)+proj(36x36)+mlp1(144x36)+mlp2(36x144)
    ConvDescs cd;
    cd.d[0] = { qkv_w  + (size_t)l * 1152 * 3456, wq,  1152, 3456, 108, 0 };
    cd.d[1] = { proj_w + (size_t)l * 1152 * 1152, wp,  1152, 1152,  36, 3888 };
    cd.d[2] = { mlp_w1 + (size_t)l * 1152 * 4608, wm1, 1152, 4608, 144, 3888 + 1296 };
    cd.d[3] = { mlp_w2 + (size_t)l * 4608 * 1152, wm2, 4608, 1152,  36, 3888 + 1296 + 5184 };
    k_convw4<<<3888 + 1296 + 5184 + 5184, 256, 0, stream>>>(cd);

    const float* ab = ada_b + (size_t)l * 6912;
    k_ada<<<dim3(108, 16), 256, 0, stream>>>(scb, ada_w + (size_t)l * 1152 * 6912, ab, mod, 6912);

    // attention branch
    k_ln_mod<<<4096, 256, 0, stream>>>(h, mod, 6912, 0, 1152, xmod);
    mfma_gemm<4, 4, 0, __bf16><<<dim3(27, 32), 256, 0, stream>>>(
        xmod, wq, qkv_b + (size_t)l * 3456, big, nullptr, 0, 1152, 1152, 3456);
    k_attn<<<4096, 256, 0, stream>>>(big, xmod);
    mfma_gemm<4, 2, 2, float><<<dim3(18, 32, 2), 256, 0, stream>>>(
        xmod, wp, proj_b + (size_t)l * 1152, h, mod + 2304, 6912, 576, 1152, 1152);

    // mlp branch
    k_ln_mod<<<4096, 256, 0, stream>>>(h, mod, 6912, 3456, 4608, xmod);
    mfma_gemm<4, 4, 1, __bf16><<<dim3(36, 32), 256, 0, stream>>>(
        xmod, wm1, mlp_b1 + (size_t)l * 4608, big, nullptr, 0, 1152, 1152, 4608);
    mfma_gemm<4, 2, 2, float><<<dim3(18, 32, 2), 256, 0, stream>>>(
        big, wm2, mlp_b2 + (size_t)l * 1152, h, mod + 5760, 6912, 2304, 4608, 1152);
  }

  k_ada<<<dim3(36, 16), 256, 0, stream>>>(scb, fl_ada_w, fl_ada_b, flm, 2304);
  k_final<<<4096, 256, 0, stream>>>(h, flm, fl_w, fl_b, out);
}

// Round 5
// 1053.397 us; speedup vs baseline: 1.1773x; 1.1773x over previous
//
#include <hip/hip_runtime.h>
#include <cmath>

static constexpr int kHid = 1152;
static constexpr int kM   = 4096;   // B * N tokens

typedef __bf16 bf16x8 __attribute__((ext_vector_type(8)));
typedef float  f32x4  __attribute__((ext_vector_type(4)));

struct BicW { float w[16][4]; };

__device__ __forceinline__ float dev_silu(float x) { return x / (1.0f + expf(-x)); }
__device__ __forceinline__ float dev_gelu(float x) {
  float u = 0.7978845608028654f * (x + 0.044715f * x * x * x);
  return 0.5f * x * (1.0f + tanhf(u));
}

__device__ __forceinline__ void glds16(const void* g, void* l) {
  __builtin_amdgcn_global_load_lds(
      (const __attribute__((address_space(1))) unsigned int*)g,
      (__attribute__((address_space(3))) unsigned int*)l, 16, 0, 0);
}

// ---------------- patch embed + bicubic pos embed (fp32 h) ----------------
__global__ __launch_bounds__(256) void k_patch_pos(
    const float* __restrict__ x, const float* __restrict__ pw,
    const float* __restrict__ pb, const float* __restrict__ pos,
    float* __restrict__ h, BicW W)
{
  const int total = kM * kHid;
  for (int idx = blockIdx.x * blockDim.x + threadIdx.x; idx < total;
       idx += gridDim.x * blockDim.x) {
    int c  = idx % kHid;
    int t  = idx / kHid;
    int b  = t >> 8;
    int gy = (t >> 4) & 15;
    int gx = t & 15;
    float acc = pb[c];
    const float* xb  = x + (size_t)b * 4 * 1024;
    const float* pwc = pw + (size_t)c * 16;
#pragma unroll
    for (int ic = 0; ic < 4; ic++)
#pragma unroll
      for (int p = 0; p < 2; p++)
#pragma unroll
        for (int q = 0; q < 2; q++)
          acc += xb[ic * 1024 + (gy * 2 + p) * 32 + gx * 2 + q] *
                 pwc[(ic * 2 + p) * 2 + q];
    float pe = 0.f;
#pragma unroll
    for (int iy = 0; iy < 4; iy++) {
      float ra = 0.f;
#pragma unroll
      for (int ix = 0; ix < 4; ix++)
        ra += W.w[gx][ix] * pos[(iy * 4 + ix) * kHid + c];
      pe += W.w[gy][iy] * ra;
    }
    h[idx] = acc + pe;
  }
}

// ---------------- timestep embedding, K-split: grid (18, B) ----------------
__global__ __launch_bounds__(256) void k_temb1(
    const float* __restrict__ t, const float* __restrict__ w1,
    const float* __restrict__ b1, float* __restrict__ hid1)
{
  int b  = blockIdx.y;
  int j0 = blockIdx.x * 64;
  int tid = threadIdx.x;
  __shared__ float e[256];
  if (tid < 128) {
    float fr  = expf(-9.210340371976184f * (float)tid / 128.0f);
    float arg = t[b] * fr;
    e[tid]       = cosf(arg);
    e[tid + 128] = sinf(arg);
  }
  __syncthreads();
  int j = tid & 63, ks = tid >> 6;
  float acc = 0.f;
#pragma unroll 4
  for (int k = ks * 64; k < ks * 64 + 64; k++)
    acc += e[k] * w1[k * kHid + j0 + j];
  __shared__ float part[4][64];
  part[ks][j] = acc;
  __syncthreads();
  if (ks == 0) {
    float v = part[0][j] + part[1][j] + part[2][j] + part[3][j] + b1[j0 + j];
    hid1[b * kHid + j0 + j] = dev_silu(v);
  }
}

__global__ __launch_bounds__(256) void k_temb2(
    const float* __restrict__ hid1, const float* __restrict__ w2,
    const float* __restrict__ b2, const float* __restrict__ ytab,
    const int* __restrict__ y, float* __restrict__ c, float* __restrict__ sc)
{
  int b  = blockIdx.y;
  int j0 = blockIdx.x * 64;
  __shared__ float hs[kHid];
  for (int k = threadIdx.x; k < kHid; k += 256) hs[k] = hid1[b * kHid + k];
  __syncthreads();
  int j = threadIdx.x & 63, ks = threadIdx.x >> 6;
  float acc = 0.f;
#pragma unroll 4
  for (int k = ks * 288; k < ks * 288 + 288; k++)
    acc += hs[k] * w2[(size_t)k * kHid + j0 + j];
  __shared__ float part[4][64];
  part[ks][j] = acc;
  __syncthreads();
  if (ks == 0) {
    int jj = j0 + j;
    float v = part[0][j] + part[1][j] + part[2][j] + part[3][j] + b2[jj] +
              ytab[(size_t)y[b] * kHid + jj];
    c[b * kHid + jj]  = v;
    sc[b * kHid + jj] = dev_silu(v);
  }
}

// ------- small matmul (16 x 1152) @ (1152 x Nout) + bias, K-split: grid (Nout/64, B)
__global__ __launch_bounds__(256) void k_ada(
    const float* __restrict__ scb, const float* __restrict__ w,
    const float* __restrict__ bias, float* __restrict__ out, int Nout)
{
  int b  = blockIdx.y;
  int j0 = blockIdx.x * 64;
  __shared__ float cs[kHid];
  for (int k = threadIdx.x; k < kHid; k += 256) cs[k] = scb[b * kHid + k];
  __syncthreads();
  int j = threadIdx.x & 63, ks = threadIdx.x >> 6;
  float acc = 0.f;
#pragma unroll 4
  for (int k = ks * 288; k < ks * 288 + 288; k++)
    acc += cs[k] * w[(size_t)k * Nout + j0 + j];
  __shared__ float part[4][64];
  part[ks][j] = acc;
  __syncthreads();
  if (ks == 0)
    out[(size_t)b * Nout + j0 + j] =
        part[0][j] + part[1][j] + part[2][j] + part[3][j] + bias[j0 + j];
}

// ------- fused weight convert+transpose for 4 matrices: W[K,N] f32 -> Wt[N,K] bf16
struct ConvDesc { const float* src; __bf16* dst; int K, N, tilesX; int start; };
struct ConvDescs { ConvDesc d[4]; };

__global__ __launch_bounds__(256) void k_convw4(ConvDescs cd)
{
  int bid = blockIdx.x;
  int e = 0;
#pragma unroll
  for (int i = 1; i < 4; i++) if (bid >= cd.d[i].start) e = i;
  const ConvDesc& D = cd.d[e];
  int lid = bid - D.start;
  int tx = lid % D.tilesX, ty = lid / D.tilesX;
  int n0 = tx * 32, k0 = ty * 32;
  __shared__ float tile[32][33];
  int c = threadIdx.x & 31, r = threadIdx.x >> 5;   // 8 rows per pass
#pragma unroll
  for (int i = 0; i < 32; i += 8)
    tile[r + i][c] = D.src[(size_t)(k0 + r + i) * D.N + n0 + c];
  __syncthreads();
#pragma unroll
  for (int i = 0; i < 32; i += 8) {
    int nn = r + i;
    D.dst[(size_t)(n0 + nn) * D.K + k0 + c] = (__bf16)tile[c][nn];
  }
}

// ---------------- LN + modulate -> bf16 ----------------
__global__ __launch_bounds__(256) void k_ln_mod(
    const float* __restrict__ h, const float* __restrict__ mod, int mstride,
    int sh_off, int sc_off, __bf16* __restrict__ out)
{
  int token = blockIdx.x;
  int b = token >> 8;
  const float* x = h + (size_t)token * kHid;
  float s = 0.f, ss = 0.f;
  for (int c = threadIdx.x; c < kHid; c += 256) {
    float v = x[c]; s += v; ss += v * v;
  }
#pragma unroll
  for (int o = 32; o > 0; o >>= 1) {
    s += __shfl_down(s, o, 64); ss += __shfl_down(ss, o, 64);
  }
  __shared__ float red[2][4];
  __shared__ float stats[2];
  int wave = threadIdx.x >> 6, lane = threadIdx.x & 63;
  if (lane == 0) { red[0][wave] = s; red[1][wave] = ss; }
  __syncthreads();
  if (threadIdx.x == 0) {
    float S  = red[0][0] + red[0][1] + red[0][2] + red[0][3];
    float SS = red[1][0] + red[1][1] + red[1][2] + red[1][3];
    float mean = S * (1.0f / kHid);
    float var  = SS * (1.0f / kHid) - mean * mean;
    stats[0] = mean;
    stats[1] = rsqrtf(var + 1e-6f);
  }
  __syncthreads();
  float mean = stats[0], rstd = stats[1];
  const float* shv = mod + (size_t)b * mstride + sh_off;
  const float* scv = mod + (size_t)b * mstride + sc_off;
  __bf16* o = out + (size_t)token * kHid;
  for (int c = threadIdx.x; c < kHid; c += 256) {
    float v = (x[c] - mean) * rstd;
    o[c] = (__bf16)(v * (1.f + scv[c]) + shv[c]);
  }
}

// ---------------- bf16 MFMA GEMM, BK=64, XOR-swizzled LDS ----------------
// C[M,N] = A[M,K](bf16) @ Wt[N,K]^T(bf16) + bias
// MODE 0: C=bf16 plain   MODE 1: C=bf16 gelu   MODE 2: C(f32) += gate[b]*(acc+bias)
// Swizzle: row's 16B chunk at LDS position p holds global chunk p ^ (row&7).
// LDS dest of global_load_lds stays lane-linear (wave base + lane*16); the
// permutation is applied to the GLOBAL fetch address only.
template<int RB, int CB, int MODE, typename OutT>
__global__ __launch_bounds__(256) void mfma_gemm(
    const __bf16* __restrict__ A, const __bf16* __restrict__ Wt,
    const float* __restrict__ bias, OutT* C,
    const float* __restrict__ gate, int gstride, int K, int Nout)
{
  constexpr int BM = RB * 32;
  constexpr int BN = CB * 32;
  __shared__ __attribute__((aligned(16))) __bf16 As[BM * 64];
  __shared__ __attribute__((aligned(16))) __bf16 Bs[BN * 64];

  const int tid  = threadIdx.x;
  const int lane = tid & 63;
  const int wv   = tid >> 6;
  const int wy   = wv >> 1, wx = wv & 1;
  const int l15  = lane & 15;
  const int quad = lane >> 4;
  const int m0   = blockIdx.y * BM;
  const int n0   = blockIdx.x * BN;

  f32x4 acc[RB][CB] = {};

  // staging: each wave covers 8 rows x 8 chunks (16B) per pass
  const int lrow = lane >> 3;            // row within wave's octet
  const int cpos = lane & 7;             // LDS chunk position
  const int gk   = (cpos ^ lrow) * 8;    // global k-offset (elems) [swizzle]

  for (int k0 = 0; k0 < K; k0 += 64) {
#pragma unroll
    for (int p = 0; p < BM / 32; p++) {
      int row = p * 32 + wv * 8 + lrow;
      glds16(A + (size_t)(m0 + row) * K + k0 + gk, &As[row * 64 + cpos * 8]);
    }
#pragma unroll
    for (int p = 0; p < BN / 32; p++) {
      int row = p * 32 + wv * 8 + lrow;
      glds16(Wt + (size_t)(n0 + row) * K + k0 + gk, &Bs[row * 64 + cpos * 8]);
    }
    __syncthreads();

#pragma unroll
    for (int ks = 0; ks < 2; ks++) {
      const int perm = ((ks * 4 + quad) ^ (l15 & 7)) * 8;
      bf16x8 af[RB], bf[CB];
#pragma unroll
      for (int r = 0; r < RB; r++)
        af[r] = *(const bf16x8*)&As[(wy * RB * 16 + r * 16 + l15) * 64 + perm];
#pragma unroll
      for (int c2 = 0; c2 < CB; c2++)
        bf[c2] = *(const bf16x8*)&Bs[(wx * CB * 16 + c2 * 16 + l15) * 64 + perm];
#pragma unroll
      for (int r = 0; r < RB; r++)
#pragma unroll
        for (int c2 = 0; c2 < CB; c2++)
          acc[r][c2] = __builtin_amdgcn_mfma_f32_16x16x32_bf16(af[r], bf[c2], acc[r][c2], 0, 0, 0);
    }
    __syncthreads();
  }

  const int bidx = m0 >> 8;
#pragma unroll
  for (int c2 = 0; c2 < CB; c2++) {
    int col = n0 + wx * CB * 16 + c2 * 16 + l15;
    float bcol = bias[col];
    float gv = (MODE == 2) ? gate[(size_t)bidx * gstride + col] : 0.f;
#pragma unroll
    for (int r = 0; r < RB; r++) {
      int mbase = m0 + wy * RB * 16 + r * 16 + quad * 4;
#pragma unroll
      for (int reg = 0; reg < 4; reg++) {
        float v = acc[r][c2][reg] + bcol;
        size_t off = (size_t)(mbase + reg) * Nout + col;
        if (MODE == 0) C[off] = (OutT)v;
        if (MODE == 1) C[off] = (OutT)dev_gelu(v);
        if (MODE == 2) C[off] = C[off] + (OutT)(gv * v);
      }
    }
  }
}

// ---------------- neighborhood attention (WIN=4, 16 heads, dh=72), bf16 io ------
__global__ __launch_bounds__(256) void k_attn(const __bf16* __restrict__ qkv,
                                              __bf16* __restrict__ out)
{
  int token = blockIdx.x;
  int b = token >> 8;
  int i = (token >> 4) & 15;
  int j = token & 15;
  int si = min(max(i - 2, 0), 12);
  int sj = min(max(j - 2, 0), 12);
  __shared__ float att[16][17];
  __shared__ float prob[16][17];

  int hh = threadIdx.x >> 4;
  int pq = threadIdx.x & 15;
  int ni = si + (pq >> 2);
  int nj = sj + (pq & 3);
  int ntok = (b << 8) | (ni << 4) | nj;
  const __bf16* qp = qkv + (size_t)token * 3456 + hh * 72;
  const __bf16* kp = qkv + (size_t)ntok  * 3456 + kHid + hh * 72;
  float s = 0.f;
#pragma unroll
  for (int dc = 0; dc < 9; dc++) {
    bf16x8 qv = *(const bf16x8*)(qp + dc * 8);
    bf16x8 kv = *(const bf16x8*)(kp + dc * 8);
#pragma unroll
    for (int d = 0; d < 8; d++) s += (float)qv[d] * (float)kv[d];
  }
  att[hh][pq] = s * 0.11785113019775793f;  // 72^-0.5
  __syncthreads();
  if (threadIdx.x < 16) {
    int hd = threadIdx.x;
    float m = att[hd][0];
    for (int e2 = 1; e2 < 16; e2++) m = fmaxf(m, att[hd][e2]);
    float sum = 0.f;
    for (int e2 = 0; e2 < 16; e2++) {
      float ex = expf(att[hd][e2] - m);
      prob[hd][e2] = ex;
      sum += ex;
    }
    float inv = 1.f / sum;
    for (int e2 = 0; e2 < 16; e2++) prob[hd][e2] *= inv;
  }
  __syncthreads();
  // PV: 144 active threads, (head, d-chunk of 8)
  if (threadIdx.x < 144) {
    int hd = threadIdx.x / 9;
    int dc = threadIdx.x - hd * 9;
    float a8[8] = {};
#pragma unroll
    for (int e2 = 0; e2 < 16; e2++) {
      int nt = (b << 8) | ((si + (e2 >> 2)) << 4) | (sj + (e2 & 3));
      bf16x8 vv = *(const bf16x8*)(qkv + (size_t)nt * 3456 + 2304 + hd * 72 + dc * 8);
      float p = prob[hd][e2];
#pragma unroll
      for (int d = 0; d < 8; d++) a8[d] += p * (float)vv[d];
    }
    bf16x8 ov;
#pragma unroll
    for (int d = 0; d < 8; d++) ov[d] = (__bf16)a8[d];
    *(bf16x8*)(out + (size_t)token * kHid + hd * 72 + dc * 8) = ov;
  }
}

// ---------------- final: LN + modulate + (1152->32) + unpatchify ----------------
__global__ __launch_bounds__(256) void k_final(
    const float* __restrict__ h, const float* __restrict__ flm,
    const float* __restrict__ fw, const float* __restrict__ fb,
    float* __restrict__ out)
{
  int token = blockIdx.x;
  int b = token >> 8;
  const float* x = h + (size_t)token * kHid;
  float s = 0.f, ss = 0.f;
  for (int c = threadIdx.x; c < kHid; c += 256) { float v = x[c]; s += v; ss += v * v; }
#pragma unroll
  for (int o = 32; o > 0; o >>= 1) {
    s += __shfl_down(s, o, 64); ss += __shfl_down(ss, o, 64);
  }
  __shared__ float red[2][4];
  __shared__ float stats[2];
  __shared__ float xs[kHid];
  int wave = threadIdx.x >> 6, lane = threadIdx.x & 63;
  if (lane == 0) { red[0][wave] = s; red[1][wave] = ss; }
  __syncthreads();
  if (threadIdx.x == 0) {
    float S  = red[0][0] + red[0][1] + red[0][2] + red[0][3];
    float SS = red[1][0] + red[1][1] + red[1][2] + red[1][3];
    float mean = S * (1.0f / kHid);
    float var  = SS * (1.0f / kHid) - mean * mean;
    stats[0] = mean; stats[1] = rsqrtf(var + 1e-6f);
  }
  __syncthreads();
  float mean = stats[0], rstd = stats[1];
  const float* shv = flm + (size_t)b * 2304;
  const float* scv = shv + kHid;
  for (int c = threadIdx.x; c < kHid; c += 256)
    xs[c] = ((x[c] - mean) * rstd) * (1.f + scv[c]) + shv[c];
  __syncthreads();
  if (threadIdx.x < 32) {
    int jj = threadIdx.x;
    float acc = fb[jj];
    for (int k = 0; k < kHid; k++) acc += xs[k] * fw[k * 32 + jj];
    int p = jj >> 4, q = (jj >> 3) & 1, cc = jj & 7;
    int gy = (token >> 4) & 15, gx = token & 15;
    out[(((size_t)b * 8 + cc) * 32 + (gy * 2 + p)) * 32 + (gx * 2 + q)] = acc;
  }
}

extern "C" void kernel_launch(void* const* d_in, const int* in_sizes, int n_in,
                              void* d_out, int out_size, void* d_ws, size_t ws_size,
                              hipStream_t stream)
{
  const float* x        = (const float*)d_in[0];
  const float* t        = (const float*)d_in[1];
  const int*   y        = (const int*)  d_in[2];
  const float* pos      = (const float*)d_in[3];
  const float* patch_w  = (const float*)d_in[4];
  const float* patch_b  = (const float*)d_in[5];
  const float* t_w1     = (const float*)d_in[6];
  const float* t_b1     = (const float*)d_in[7];
  const float* t_w2     = (const float*)d_in[8];
  const float* t_b2     = (const float*)d_in[9];
  const float* y_table  = (const float*)d_in[10];
  const float* ada_w    = (const float*)d_in[11];
  const float* ada_b    = (const float*)d_in[12];
  const float* qkv_w    = (const float*)d_in[13];
  const float* qkv_b    = (const float*)d_in[14];
  const float* proj_w   = (const float*)d_in[15];
  const float* proj_b   = (const float*)d_in[16];
  const float* mlp_w1   = (const float*)d_in[17];
  const float* mlp_b1   = (const float*)d_in[18];
  const float* mlp_w2   = (const float*)d_in[19];
  const float* mlp_b2   = (const float*)d_in[20];
  const float* fl_ada_w = (const float*)d_in[21];
  const float* fl_ada_b = (const float*)d_in[22];
  const float* fl_w     = (const float*)d_in[23];
  const float* fl_b     = (const float*)d_in[24];
  float* out = (float*)d_out;

  // workspace carve-up
  float* ws   = (float*)d_ws;
  float*  h    = ws;                                   // 4096*1152 f32
  __bf16* xmod = (__bf16*)(h + (size_t)4096 * 1152);   // 4096*1152 bf16
  __bf16* big  = xmod + (size_t)4096 * 1152;           // 4096*4608 bf16
  __bf16* wq   = big  + (size_t)4096 * 4608;           // 3456*1152 bf16
  __bf16* wp   = wq   + (size_t)3456 * 1152;           // 1152*1152 bf16
  __bf16* wm1  = wp   + (size_t)1152 * 1152;           // 4608*1152 bf16
  __bf16* wm2  = wm1  + (size_t)4608 * 1152;           // 1152*4608 bf16
  float*  cbuf = (float*)(wm2 + (size_t)1152 * 4608);  // 16*1152
  float*  scb  = cbuf + 16 * 1152;
  float*  hid1 = scb  + 16 * 1152;
  float*  mod  = hid1 + 16 * 1152;                     // 16*6912
  float*  flm  = mod  + 16 * 6912;                     // 16*2304

  // bicubic (Keys a=-0.5) 4->16 resize weights, jax semantics, row-normalized
  BicW W;
  for (int o = 0; o < 16; o++) {
    double sf = (o + 0.5) * 0.25 - 0.5;
    double wd[4]; double tot = 0.0;
    const double a = -0.5;
    for (int i = 0; i < 4; i++) {
      double d = fabs(sf - (double)i);
      double v;
      if (d <= 1.0)      v = ((a + 2.0) * d - (a + 3.0)) * d * d + 1.0;
      else if (d < 2.0)  v = a * (((d - 5.0) * d + 8.0) * d - 4.0);
      else               v = 0.0;
      wd[i] = v; tot += v;
    }
    for (int i = 0; i < 4; i++) W.w[o][i] = (float)(wd[i] / tot);
  }

  k_patch_pos<<<4608, 256, 0, stream>>>(x, patch_w, patch_b, pos, h, W);
  k_temb1<<<dim3(18, 16), 256, 0, stream>>>(t, t_w1, t_b1, hid1);
  k_temb2<<<dim3(18, 16), 256, 0, stream>>>(hid1, t_w2, t_b2, y_table, y, cbuf, scb);

  for (int l = 0; l < 2; l++) {
    // fused weight convert: qkv(108x36)+proj(36x36)+mlp1(144x36)+mlp2(36x144)
    ConvDescs cd;
    cd.d[0] = { qkv_w  + (size_t)l * 1152 * 3456, wq,  1152, 3456, 108, 0 };
    cd.d[1] = { proj_w + (size_t)l * 1152 * 1152, wp,  1152, 1152,  36, 3888 };
    cd.d[2] = { mlp_w1 + (size_t)l * 1152 * 4608, wm1, 1152, 4608, 144, 3888 + 1296 };
    cd.d[3] = { mlp_w2 + (size_t)l * 4608 * 1152, wm2, 4608, 1152,  36, 3888 + 1296 + 5184 };
    k_convw4<<<3888 + 1296 + 5184 + 5184, 256, 0, stream>>>(cd);

    const float* ab = ada_b + (size_t)l * 6912;
    k_ada<<<dim3(108, 16), 256, 0, stream>>>(scb, ada_w + (size_t)l * 1152 * 6912, ab, mod, 6912);

    // attention branch
    k_ln_mod<<<4096, 256, 0, stream>>>(h, mod, 6912, 0, 1152, xmod);
    mfma_gemm<4, 4, 0, __bf16><<<dim3(27, 32), 256, 0, stream>>>(
        xmod, wq, qkv_b + (size_t)l * 3456, big, nullptr, 0, 1152, 3456);
    k_attn<<<4096, 256, 0, stream>>>(big, xmod);
    mfma_gemm<4, 2, 2, float><<<dim3(18, 32), 256, 0, stream>>>(
        xmod, wp, proj_b + (size_t)l * 1152, h, mod + 2304, 6912, 1152, 1152);

    // mlp branch
    k_ln_mod<<<4096, 256, 0, stream>>>(h, mod, 6912, 3456, 4608, xmod);
    mfma_gemm<4, 4, 1, __bf16><<<dim3(36, 32), 256, 0, stream>>>(
        xmod, wm1, mlp_b1 + (size_t)l * 4608, big, nullptr, 0, 1152, 4608);
    mfma_gemm<4, 2, 2, float><<<dim3(18, 32), 256, 0, stream>>>(
        big, wm2, mlp_b2 + (size_t)l * 1152, h, mod + 5760, 6912, 4608, 1152);
  }

  k_ada<<<dim3(36, 16), 256, 0, stream>>>(scb, fl_ada_w, fl_ada_b, flm, 2304);
  k_final<<<4096, 256, 0, stream>>>(h, flm, fl_w, fl_b, out);
}